// Round 5
// baseline (536.389 us; speedup 1.0000x reference)
//
#include <hip/hip_runtime.h>
#include <cstdint>

#define NAG 25
#define EHH 3200      // EHH_HID
#define KDIM 800      // N_AGENT*N_S
#define BATCH 2048
#define NEDGE 300
#define NPAD 384      // 300 padded to 3x128
#define KSPLIT 5
#define GRID 256      // one block per CU -> co-residency guaranteed for sw barrier

typedef _Float16 half8 __attribute__((ext_vector_type(8)));
typedef float f32x4 __attribute__((ext_vector_type(4)));

__device__ __forceinline__ float leaky(float x) { return x >= 0.f ? x : 0.01f * x; }

__device__ __forceinline__ void async16(const void* g, void* l) {
    __builtin_amdgcn_global_load_lds(
        (const __attribute__((address_space(1))) void*)(uintptr_t)g,
        (__attribute__((address_space(3))) void*)(unsigned)(uintptr_t)l, 16, 0, 0);
}

// ---- software grid barrier (ROCm cg-style): release fence, arrive, acquire spin ----
__device__ __forceinline__ void gbar(int* c) {
    __syncthreads();
    __threadfence();                       // release: this block's writes visible device-wide
    if (threadIdx.x == 0) {
        atomicAdd(c, 1);                   // device-scope by default [m20]
        while (__hip_atomic_load(c, __ATOMIC_ACQUIRE, __HIP_MEMORY_SCOPE_AGENT) < GRID)
            __builtin_amdgcn_s_sleep(8);
    }
    __syncthreads();
    __threadfence();                       // acquire: order subsequent loads, drop stale L1
}

__global__ void binit(int* cnt) { if (threadIdx.x < 8) cnt[threadIdx.x] = 0; }

// ---- one 128x128 MFMA tile, C = A(MxK) * B^T(NxK), double-buffered LDS ----
template <bool LEAKY_F16_OUT>
__device__ void gemm_tile(const _Float16* __restrict__ A, const _Float16* __restrict__ B,
                          _Float16* __restrict__ Ch, float* __restrict__ Cf,
                          int Ktot, int ldc, int nk, int m0, int n0, int k0,
                          _Float16* As, _Float16* Bs, int tid) {
    const int lane = tid & 63;
    const int wave = tid >> 6;            // 4 waves, 2x2
    const int wm = (wave >> 1) << 6;
    const int wn = (wave & 1) << 6;
    const int srow = lane >> 2;
    const int scol = (lane & 3) << 3;
    const _Float16* gA0 = A + (size_t)(m0 + wave * 16 + srow) * Ktot + k0 + scol;
    const _Float16* gA1 = gA0 + (size_t)64 * Ktot;
    const _Float16* gB0 = B + (size_t)(n0 + wave * 16 + srow) * Ktot + k0 + scol;
    const _Float16* gB1 = gB0 + (size_t)64 * Ktot;
    const int lofs = wave * 512;

    f32x4 acc[4][4];
    const f32x4 zero = {0.f, 0.f, 0.f, 0.f};
#pragma unroll
    for (int i = 0; i < 4; ++i)
#pragma unroll
        for (int j = 0; j < 4; ++j) acc[i][j] = zero;

    const int fr = lane & 15;
    const int q8 = (lane >> 4) << 3;

    __syncthreads();   // prior users of As/Bs (e.g. previous tile's readers) done
    async16(gA0, As + lofs);
    async16(gA1, As + 2048 + lofs);
    async16(gB0, Bs + lofs);
    async16(gB1, Bs + 2048 + lofs);

    for (int kt = 0; kt < nk; ++kt) {
        const int cur = (kt & 1) * 4096;
        __syncthreads();   // buf[cur] staged; readers of other buf done
        if (kt + 1 < nk) {
            const int ko = (kt + 1) << 5;
            const int nxt = 4096 - cur;
            async16(gA0 + ko, As + nxt + lofs);
            async16(gA1 + ko, As + nxt + 2048 + lofs);
            async16(gB0 + ko, Bs + nxt + lofs);
            async16(gB1 + ko, Bs + nxt + 2048 + lofs);
        }
        half8 av[4], bv[4];
#pragma unroll
        for (int i = 0; i < 4; ++i)
            av[i] = *(const half8*)(As + cur + (wm + i * 16 + fr) * 32 + q8);
#pragma unroll
        for (int j = 0; j < 4; ++j)
            bv[j] = *(const half8*)(Bs + cur + (wn + j * 16 + fr) * 32 + q8);
#pragma unroll
        for (int i = 0; i < 4; ++i)
#pragma unroll
            for (int j = 0; j < 4; ++j)
                acc[i][j] = __builtin_amdgcn_mfma_f32_16x16x32_f16(av[i], bv[j], acc[i][j], 0, 0, 0);
    }

    // C/D layout: col = lane&15, row = (lane>>4)*4 + reg  [m89-verified]
    const int r0 = (lane >> 4) << 2;
#pragma unroll
    for (int i = 0; i < 4; ++i)
#pragma unroll
        for (int j = 0; j < 4; ++j)
#pragma unroll
            for (int r = 0; r < 4; ++r) {
                int row = m0 + wm + i * 16 + r0 + r;
                int col = n0 + wn + j * 16 + fr;
                if (LEAKY_F16_OUT)
                    Ch[(size_t)row * ldc + col] = (_Float16)leaky(acc[i][j][r]);
                else
                    Cf[(size_t)row * ldc + col] = acc[i][j][r];
            }
}

__global__ __launch_bounds__(256, 2)
void mega(const float* __restrict__ states, const float* __restrict__ ehh_w,
          const float* __restrict__ anova, const float* __restrict__ w1,
          const float* __restrict__ b1, const float* __restrict__ w2,
          const float* __restrict__ b2, const float* __restrict__ w3,
          const float* __restrict__ b3, const int* __restrict__ actions,
          const int* __restrict__ adj, float* __restrict__ out,
          char* __restrict__ ws) {
    __shared__ __attribute__((aligned(16))) char smem[32768];
    float*     pacc = (float*)ws;                          // 16x800 sums + 16x800 sqs
    float*     mrs  = (float*)(ws + 102400);               // 800 mean + 800 rsqrt
    int*       wsrc = (int*)(ws + 108800);                 // 3200 winner-src (-1 none)
    int*       cnt  = (int*)(ws + 121600);                 // 8 barrier counters
    _Float16*  Abf  = (_Float16*)(ws + 122880);            // 2048x800
    _Float16*  WbT  = (_Float16*)(ws + 3399680);           // 3200x800
    _Float16*  W2dT = (_Float16*)(ws + 8519680);           // 384x3200
    _Float16*  emb  = (_Float16*)(ws + 10977280);          // 2048x3200
    float*     Hp   = (float*)(ws + 24084480);             // KSPLIT x 2048x384 f32

    const int tid = threadIdx.x;
    const int bid = blockIdx.x;

    // ---- P1: batch-norm partial stats (400 units, grid-stride) ----
    for (int vt = bid; vt < 400; vt += GRID) {
        float* ls = (float*)smem;
        float* lq = ls + 256;
        int a = vt % 25, chunk = vt / 25;
        int s = tid & 31, ty = tid >> 5;
        const float* base = states + ((size_t)a * BATCH + chunk * 128) * 32 + s;
        float sum = 0.f, sq = 0.f;
        for (int b = ty; b < 128; b += 8) {
            float v = base[(size_t)b * 32];
            sum += v; sq += v * v;
        }
        __syncthreads();
        ls[ty * 32 + s] = sum; lq[ty * 32 + s] = sq;
        __syncthreads();
        if (ty == 0) {
#pragma unroll
            for (int i = 1; i < 8; ++i) { sum += ls[i * 32 + s]; sq += lq[i * 32 + s]; }
            pacc[chunk * 800 + a * 32 + s] = sum;
            pacc[12800 + chunk * 800 + a * 32 + s] = sq;
        }
    }
    gbar(cnt + 0);

    // ---- P2: finalize mean/rsqrt; edge-winner scan (last sequential writer wins) ----
    if (bid < 4) {
        int f = bid * 256 + tid;
        if (f < 800) {
            float s = 0.f, q = 0.f;
#pragma unroll
            for (int c = 0; c < 16; ++c) { s += pacc[c * 800 + f]; q += pacc[12800 + c * 800 + f]; }
            float m = s * (1.f / BATCH);
            float var = q * (1.f / BATCH) - m * m;
            mrs[f] = m;
            mrs[800 + f] = rsqrtf(var + 1e-5f);
        }
    } else if (bid < 17) {
        int h = (bid - 4) * 256 + tid;
        if (h < EHH) {
            int win = -1;
            for (int e = 0; e < NEDGE; ++e) if (adj[e * 4 + 1] == h) win = e;
            for (int e = 0; e < NEDGE; ++e) if (adj[e * 4 + 3] == h) win = NEDGE + e;
            wsrc[h] = win >= 0 ? adj[(win >= NEDGE ? win - NEDGE : win) * 4] : -1;
        }
    }
    gbar(cnt + 1);

    // ---- P3: prep = norma [0,6400) | wtrans [6400,8900) | w2d [8900,9213) | pad [9213,9345) ----
    for (int vt = bid; vt < 9345; vt += GRID) {
        if (vt < 6400) {
            int t = vt * 256 + tid;   // t = b*800 + f
            int b = t / KDIM;
            int f = t - b * KDIM;
            int a = f >> 5, s = f & 31;
            float v = states[((size_t)a * BATCH + b) * 32 + s];
            Abf[t] = (_Float16)((v - mrs[f]) * mrs[800 + f]);
        } else if (vt < 8900) {
            float* tile = (float*)smem;   // 32x33
            int bb = vt - 6400;
            int n0 = (bb % 100) * 32, k0 = (bb / 100) * 32;
            int x = tid & 31, y = tid >> 5;
            __syncthreads();   // previous iteration's readers done
            for (int i = y; i < 32; i += 8)
                tile[i * 33 + x] = ehh_w[(size_t)(k0 + i) * EHH + n0 + x];
            __syncthreads();
            for (int i = y; i < 32; i += 8)
                WbT[(size_t)(n0 + i) * KDIM + k0 + x] = (_Float16)tile[x * 33 + i];
        } else if (vt < 9213) {
            int t = (vt - 8900) * 256 + tid;   // t = a*3200 + h
            if (t < NAG * EHH) {
                int a = t / EHH, h = t - a * EHH;
                float att = anova[(size_t)h * NAG + a];
                int src = wsrc[h];
                if (src >= 0) att += anova[(size_t)(EHH + src) * NAG + a];
                const float* wp = w1 + ((size_t)a * EHH + h) * 12;
#pragma unroll
                for (int kk = 0; kk < 12; ++kk)
                    W2dT[(size_t)(a * 12 + kk) * EHH + h] = (_Float16)(att * wp[kk]);
            }
        } else {
            int p = (vt - 9213) * 256 + tid;
            if (p < (NPAD - 300) * EHH / 8) {
                half8 z = {0, 0, 0, 0, 0, 0, 0, 0};
                ((half8*)(W2dT + (size_t)300 * EHH))[p] = z;
            }
        }
    }
    gbar(cnt + 2);

    // ---- P4: GEMM1 emb = leaky(Abf @ WbT^T)  M=2048 N=3200 K=800 (400 tiles) ----
    _Float16* As = (_Float16*)smem;
    _Float16* Bs = As + 8192;
    for (int vt = bid; vt < 400; vt += GRID) {
        int m0 = (vt & 15) << 7;
        int n0 = (vt >> 4) << 7;
        gemm_tile<true>(Abf, WbT, emb, nullptr, KDIM, EHH, 25, m0, n0, 0, As, Bs, tid);
    }
    gbar(cnt + 3);

    // ---- P5: GEMM2 split-K x5: Hp[z] = emb @ W2dT^T  M=2048 N=384 K=3200 (240 tiles) ----
    if (bid < 240) {
        int m0 = (bid & 15) << 7;
        int n0 = ((bid >> 4) % 3) << 7;
        int bz = bid / 48;
        gemm_tile<false>(emb, W2dT, nullptr, Hp + (size_t)bz * BATCH * NPAD,
                         EHH, NPAD, EHH / KSPLIT / 32, m0, n0, bz * (EHH / KSPLIT), As, Bs, tid);
    }
    gbar(cnt + 4);

    // ---- P6: tail — reduce split-K, bias+leaky, 12x12, 12x4, action gather ----
    if (bid < 200) {
        int t = bid * 256 + tid;   // t = a*2048 + b
        int b = t & (BATCH - 1);
        int a = t >> 11;
        const float* hp = Hp + (size_t)b * NPAD + a * 12;
        float h1v[12];
#pragma unroll
        for (int k = 0; k < 12; ++k) {
            float s = b1[a * 12 + k];
#pragma unroll
            for (int ks = 0; ks < KSPLIT; ++ks) s += hp[(size_t)ks * BATCH * NPAD + k];
            h1v[k] = leaky(s);
        }
        float h2v[12];
#pragma unroll
        for (int j = 0; j < 12; ++j) {
            float s = b2[a * 12 + j];
#pragma unroll
            for (int k = 0; k < 12; ++k) s += h1v[k] * w2[(a * 12 + k) * 12 + j];
            h2v[j] = leaky(s);
        }
        int c = actions[t];
        float q = b3[a * 4 + c];
#pragma unroll
        for (int j = 0; j < 12; ++j) q += h2v[j] * w3[(a * 12 + j) * 4 + c];
        out[t] = q;
    }
}

extern "C" void kernel_launch(void* const* d_in, const int* in_sizes, int n_in,
                              void* d_out, int out_size, void* d_ws, size_t ws_size,
                              hipStream_t stream) {
    (void)in_sizes; (void)n_in; (void)out_size; (void)ws_size;
    const float* states = (const float*)d_in[0];
    const float* ehh_w  = (const float*)d_in[1];
    const float* anova  = (const float*)d_in[2];
    const float* w1     = (const float*)d_in[3];
    const float* b1     = (const float*)d_in[4];
    const float* w2     = (const float*)d_in[5];
    const float* b2     = (const float*)d_in[6];
    const float* w3     = (const float*)d_in[7];
    const float* b3     = (const float*)d_in[8];
    const int* actions  = (const int*)d_in[9];
    const int* adj      = (const int*)d_in[10];
    float* out = (float*)d_out;
    char* ws = (char*)d_ws;
    int* cnt = (int*)(ws + 121600);

    binit<<<1, 256, 0, stream>>>(cnt);
    mega<<<GRID, 256, 0, stream>>>(states, ehh_w, anova, w1, b1, w2, b2, w3, b3,
                                   actions, adj, out, ws);
}

// Round 6
// 366.079 us; speedup vs baseline: 1.4652x; 1.4652x over previous
//
#include <hip/hip_runtime.h>
#include <cstdint>

#define NAG 25
#define EHH 3200      // EHH_HID
#define KDIM 800      // N_AGENT*N_S
#define BATCH 2048
#define NEDGE 300
#define NPAD 384      // 300 padded to 3x128
#define KSPLIT 10
#define GRID 512      // 2 blocks/CU; capacity >= 5 blocks/CU at 32KB LDS -> co-residency unconditional

typedef _Float16 half8 __attribute__((ext_vector_type(8)));
typedef float f32x4 __attribute__((ext_vector_type(4)));

__device__ __forceinline__ float leaky(float x) { return x >= 0.f ? x : 0.01f * x; }

__device__ __forceinline__ void async16(const void* g, void* l) {
    __builtin_amdgcn_global_load_lds(
        (const __attribute__((address_space(1))) void*)(uintptr_t)g,
        (__attribute__((address_space(3))) void*)(unsigned)(uintptr_t)l, 16, 0, 0);
}

// ---- software grid barrier, cache-friendly ----
// R5 lesson: acquire-polling emits buffer_inv (L1+L2!) per poll -> device-wide cache thrash.
// Correct pattern: release fence ONCE (wbl2), relaxed add, relaxed polls (plain sc0sc1 load,
// no invalidation), acquire fence ONCE (inv) after the spin. Thread 0 only.
__device__ __forceinline__ void gbar(int* c) {
    __syncthreads();                       // each wave drains its stores (vmcnt0) at s_barrier
    if (threadIdx.x == 0) {
        __builtin_amdgcn_fence(__ATOMIC_RELEASE, "agent");   // publish: L2 writeback
        __hip_atomic_fetch_add(c, 1, __ATOMIC_RELAXED, __HIP_MEMORY_SCOPE_AGENT);
        while (__hip_atomic_load(c, __ATOMIC_RELAXED, __HIP_MEMORY_SCOPE_AGENT) < GRID)
            __builtin_amdgcn_s_sleep(8);
        __builtin_amdgcn_fence(__ATOMIC_ACQUIRE, "agent");   // discard stale L1/L2 once
    }
    __syncthreads();
}

__global__ void binit(int* cnt) { if (threadIdx.x < 8) cnt[threadIdx.x] = 0; }

// ---- one 128x128 MFMA tile, C = A(MxK) * B^T(NxK), double-buffered LDS ----
template <bool LEAKY_F16_OUT>
__device__ void gemm_tile(const _Float16* __restrict__ A, const _Float16* __restrict__ B,
                          _Float16* __restrict__ Ch, float* __restrict__ Cf,
                          int Ktot, int ldc, int nk, int m0, int n0, int k0,
                          _Float16* As, _Float16* Bs, int tid) {
    const int lane = tid & 63;
    const int wave = tid >> 6;            // 4 waves, 2x2
    const int wm = (wave >> 1) << 6;
    const int wn = (wave & 1) << 6;
    const int srow = lane >> 2;
    const int scol = (lane & 3) << 3;
    const _Float16* gA0 = A + (size_t)(m0 + wave * 16 + srow) * Ktot + k0 + scol;
    const _Float16* gA1 = gA0 + (size_t)64 * Ktot;
    const _Float16* gB0 = B + (size_t)(n0 + wave * 16 + srow) * Ktot + k0 + scol;
    const _Float16* gB1 = gB0 + (size_t)64 * Ktot;
    const int lofs = wave * 512;

    f32x4 acc[4][4];
    const f32x4 zero = {0.f, 0.f, 0.f, 0.f};
#pragma unroll
    for (int i = 0; i < 4; ++i)
#pragma unroll
        for (int j = 0; j < 4; ++j) acc[i][j] = zero;

    const int fr = lane & 15;
    const int q8 = (lane >> 4) << 3;

    __syncthreads();   // prior users of As/Bs done
    async16(gA0, As + lofs);
    async16(gA1, As + 2048 + lofs);
    async16(gB0, Bs + lofs);
    async16(gB1, Bs + 2048 + lofs);

    for (int kt = 0; kt < nk; ++kt) {
        const int cur = (kt & 1) * 4096;
        __syncthreads();   // buf[cur] staged; readers of other buf done
        if (kt + 1 < nk) {
            const int ko = (kt + 1) << 5;
            const int nxt = 4096 - cur;
            async16(gA0 + ko, As + nxt + lofs);
            async16(gA1 + ko, As + nxt + 2048 + lofs);
            async16(gB0 + ko, Bs + nxt + lofs);
            async16(gB1 + ko, Bs + nxt + 2048 + lofs);
        }
        half8 av[4], bv[4];
#pragma unroll
        for (int i = 0; i < 4; ++i)
            av[i] = *(const half8*)(As + cur + (wm + i * 16 + fr) * 32 + q8);
#pragma unroll
        for (int j = 0; j < 4; ++j)
            bv[j] = *(const half8*)(Bs + cur + (wn + j * 16 + fr) * 32 + q8);
#pragma unroll
        for (int i = 0; i < 4; ++i)
#pragma unroll
            for (int j = 0; j < 4; ++j)
                acc[i][j] = __builtin_amdgcn_mfma_f32_16x16x32_f16(av[i], bv[j], acc[i][j], 0, 0, 0);
    }

    // C/D layout: col = lane&15, row = (lane>>4)*4 + reg  [m89-verified]
    const int r0 = (lane >> 4) << 2;
#pragma unroll
    for (int i = 0; i < 4; ++i)
#pragma unroll
        for (int j = 0; j < 4; ++j)
#pragma unroll
            for (int r = 0; r < 4; ++r) {
                int row = m0 + wm + i * 16 + r0 + r;
                int col = n0 + wn + j * 16 + fr;
                if (LEAKY_F16_OUT)
                    Ch[(size_t)row * ldc + col] = (_Float16)leaky(acc[i][j][r]);
                else
                    Cf[(size_t)row * ldc + col] = acc[i][j][r];
            }
}

__global__ __launch_bounds__(256, 2)
void mega(const float* __restrict__ states, const float* __restrict__ ehh_w,
          const float* __restrict__ anova, const float* __restrict__ w1,
          const float* __restrict__ b1, const float* __restrict__ w2,
          const float* __restrict__ b2, const float* __restrict__ w3,
          const float* __restrict__ b3, const int* __restrict__ actions,
          const int* __restrict__ adj, float* __restrict__ out,
          char* __restrict__ ws) {
    __shared__ __attribute__((aligned(16))) char smem[32768];
    float*     pacc = (float*)ws;                          // 16x800 sums + 16x800 sqs
    float*     mrs  = (float*)(ws + 102400);               // 800 mean + 800 rsqrt
    int*       wsrc = (int*)(ws + 108800);                 // 3200 winner-src (-1 none)
    int*       cnt  = (int*)(ws + 121600);                 // 8 barrier counters
    _Float16*  Abf  = (_Float16*)(ws + 122880);            // 2048x800
    _Float16*  WbT  = (_Float16*)(ws + 3399680);           // 3200x800
    _Float16*  W2dT = (_Float16*)(ws + 8519680);           // 384x3200
    _Float16*  emb  = (_Float16*)(ws + 10977280);          // 2048x3200
    float*     Hp   = (float*)(ws + 24084480);             // KSPLIT x 2048x384 f32 (~55.5MB end)

    const int tid = threadIdx.x;
    const int bid = blockIdx.x;

    // ---- P1: batch-norm partial stats (400 units) ----
    if (bid < 400) {
        float* ls = (float*)smem;
        float* lq = ls + 256;
        int a = bid % 25, chunk = bid / 25;
        int s = tid & 31, ty = tid >> 5;
        const float* base = states + ((size_t)a * BATCH + chunk * 128) * 32 + s;
        float sum = 0.f, sq = 0.f;
        for (int b = ty; b < 128; b += 8) {
            float v = base[(size_t)b * 32];
            sum += v; sq += v * v;
        }
        ls[ty * 32 + s] = sum; lq[ty * 32 + s] = sq;
        __syncthreads();
        if (ty == 0) {
#pragma unroll
            for (int i = 1; i < 8; ++i) { sum += ls[i * 32 + s]; sq += lq[i * 32 + s]; }
            pacc[chunk * 800 + a * 32 + s] = sum;
            pacc[12800 + chunk * 800 + a * 32 + s] = sq;
        }
    }
    gbar(cnt + 0);

    // ---- P2: finalize mean/rsqrt; edge-winner scan (last sequential writer wins) ----
    if (bid < 4) {
        int f = bid * 256 + tid;
        if (f < 800) {
            float s = 0.f, q = 0.f;
#pragma unroll
            for (int c = 0; c < 16; ++c) { s += pacc[c * 800 + f]; q += pacc[12800 + c * 800 + f]; }
            float m = s * (1.f / BATCH);
            float var = q * (1.f / BATCH) - m * m;
            mrs[f] = m;
            mrs[800 + f] = rsqrtf(var + 1e-5f);
        }
    } else if (bid < 17) {
        int h = (bid - 4) * 256 + tid;
        if (h < EHH) {
            int win = -1;
            for (int e = 0; e < NEDGE; ++e) if (adj[e * 4 + 1] == h) win = e;
            for (int e = 0; e < NEDGE; ++e) if (adj[e * 4 + 3] == h) win = NEDGE + e;
            wsrc[h] = win >= 0 ? adj[(win >= NEDGE ? win - NEDGE : win) * 4] : -1;
        }
    }
    gbar(cnt + 1);

    // ---- P3: prep = norma [0,6400) | wtrans [6400,8900) | w2d [8900,9213) | pad [9213,9345) ----
    for (int vt = bid; vt < 9345; vt += GRID) {
        if (vt < 6400) {
            int t = vt * 256 + tid;   // t = b*800 + f
            int b = t / KDIM;
            int f = t - b * KDIM;
            int a = f >> 5, s = f & 31;
            float v = states[((size_t)a * BATCH + b) * 32 + s];
            Abf[t] = (_Float16)((v - mrs[f]) * mrs[800 + f]);
        } else if (vt < 8900) {
            float* tile = (float*)smem;   // 32x33
            int bb = vt - 6400;
            int n0 = (bb % 100) * 32, k0 = (bb / 100) * 32;
            int x = tid & 31, y = tid >> 5;
            __syncthreads();   // previous iteration's readers done
            for (int i = y; i < 32; i += 8)
                tile[i * 33 + x] = ehh_w[(size_t)(k0 + i) * EHH + n0 + x];
            __syncthreads();
            for (int i = y; i < 32; i += 8)
                WbT[(size_t)(n0 + i) * KDIM + k0 + x] = (_Float16)tile[x * 33 + i];
        } else if (vt < 9213) {
            int t = (vt - 8900) * 256 + tid;   // t = a*3200 + h
            if (t < NAG * EHH) {
                int a = t / EHH, h = t - a * EHH;
                float att = anova[(size_t)h * NAG + a];
                int src = wsrc[h];
                if (src >= 0) att += anova[(size_t)(EHH + src) * NAG + a];
                const float* wp = w1 + ((size_t)a * EHH + h) * 12;
#pragma unroll
                for (int kk = 0; kk < 12; ++kk)
                    W2dT[(size_t)(a * 12 + kk) * EHH + h] = (_Float16)(att * wp[kk]);
            }
        } else {
            int p = (vt - 9213) * 256 + tid;
            if (p < (NPAD - 300) * EHH / 8) {
                half8 z = {0, 0, 0, 0, 0, 0, 0, 0};
                ((half8*)(W2dT + (size_t)300 * EHH))[p] = z;
            }
        }
    }
    gbar(cnt + 2);

    // ---- P4: GEMM1 emb = leaky(Abf @ WbT^T)  M=2048 N=3200 K=800 (400 tiles, 1/block) ----
    _Float16* As = (_Float16*)smem;
    _Float16* Bs = As + 8192;
    if (bid < 400) {
        int m0 = (bid & 15) << 7;
        int n0 = (bid >> 4) << 7;
        gemm_tile<true>(Abf, WbT, emb, nullptr, KDIM, EHH, 25, m0, n0, 0, As, Bs, tid);
    }
    gbar(cnt + 3);

    // ---- P5: GEMM2 split-K x10: Hp[z] = emb @ W2dT^T  M=2048 N=384 K=3200 (480 tiles) ----
    if (bid < 480) {
        int m0 = (bid & 15) << 7;
        int n0 = ((bid >> 4) % 3) << 7;
        int bz = bid / 48;
        gemm_tile<false>(emb, W2dT, nullptr, Hp + (size_t)bz * BATCH * NPAD,
                         EHH, NPAD, EHH / KSPLIT / 32, m0, n0, bz * (EHH / KSPLIT), As, Bs, tid);
    }
    gbar(cnt + 4);

    // ---- P6: tail — reduce split-K, bias+leaky, 12x12, 12x4, action gather ----
    if (bid < 200) {
        int t = bid * 256 + tid;   // t = a*2048 + b
        int b = t & (BATCH - 1);
        int a = t >> 11;
        const float* hp = Hp + (size_t)b * NPAD + a * 12;
        float h1v[12];
#pragma unroll
        for (int k = 0; k < 12; ++k) {
            float s = b1[a * 12 + k];
#pragma unroll
            for (int ks = 0; ks < KSPLIT; ++ks) s += hp[(size_t)ks * BATCH * NPAD + k];
            h1v[k] = leaky(s);
        }
        float h2v[12];
#pragma unroll
        for (int j = 0; j < 12; ++j) {
            float s = b2[a * 12 + j];
#pragma unroll
            for (int k = 0; k < 12; ++k) s += h1v[k] * w2[(a * 12 + k) * 12 + j];
            h2v[j] = leaky(s);
        }
        int c = actions[t];
        float q = b3[a * 4 + c];
#pragma unroll
        for (int j = 0; j < 12; ++j) q += h2v[j] * w3[(a * 12 + j) * 4 + c];
        out[t] = q;
    }
}

extern "C" void kernel_launch(void* const* d_in, const int* in_sizes, int n_in,
                              void* d_out, int out_size, void* d_ws, size_t ws_size,
                              hipStream_t stream) {
    (void)in_sizes; (void)n_in; (void)out_size; (void)ws_size;
    const float* states = (const float*)d_in[0];
    const float* ehh_w  = (const float*)d_in[1];
    const float* anova  = (const float*)d_in[2];
    const float* w1     = (const float*)d_in[3];
    const float* b1     = (const float*)d_in[4];
    const float* w2     = (const float*)d_in[5];
    const float* b2     = (const float*)d_in[6];
    const float* w3     = (const float*)d_in[7];
    const float* b3     = (const float*)d_in[8];
    const int* actions  = (const int*)d_in[9];
    const int* adj      = (const int*)d_in[10];
    float* out = (float*)d_out;
    char* ws = (char*)d_ws;
    int* cnt = (int*)(ws + 121600);

    binit<<<1, 256, 0, stream>>>(cnt);
    mega<<<GRID, 256, 0, stream>>>(states, ehh_w, anova, w1, b1, w2, b2, w3, b3,
                                   actions, adj, out, ws);
}

// Round 7
// 178.578 us; speedup vs baseline: 3.0037x; 2.0500x over previous
//
#include <hip/hip_runtime.h>
#include <cstdint>

#define NAG 25
#define EHH 3200      // EHH_HID
#define KDIM 800      // N_AGENT*N_S
#define BATCH 2048
#define NEDGE 300
#define NPAD 384      // 300 padded to 3x128
#define KSPLIT 5

typedef _Float16 half8 __attribute__((ext_vector_type(8)));
typedef float f32x4 __attribute__((ext_vector_type(4)));

__device__ __forceinline__ float leaky(float x) { return x >= 0.f ? x : 0.01f * x; }

// ---------------- batch-norm partial stats: (25 agents x 16 chunks), plain stores ----------------
__global__ void stats_part(const float* __restrict__ states, float* __restrict__ pacc) {
    int a = blockIdx.x;            // agent
    int chunk = blockIdx.y;        // 128 batch rows each
    int s = threadIdx.x & 31, ty = threadIdx.x >> 5;
    const float* base = states + ((size_t)a * BATCH + chunk * 128) * 32 + s;
    float sum = 0.f, sq = 0.f;
    for (int b = ty; b < 128; b += 8) {
        float v = base[(size_t)b * 32];
        sum += v; sq += v * v;
    }
    __shared__ float ls[8][32], lq[8][32];
    ls[ty][s] = sum; lq[ty][s] = sq;
    __syncthreads();
    if (ty == 0) {
#pragma unroll
        for (int i = 1; i < 8; ++i) { sum += ls[i][s]; sq += lq[i][s]; }
        pacc[chunk * 800 + a * 32 + s] = sum;
        pacc[12800 + chunk * 800 + a * 32 + s] = sq;
    }
}

// ---------------- fused prep: norma [0,6400) | wtrans [6400,8900) | w2d [8900,9213) | pad [9213,9345) ----
// norma: per-thread redundant stats finalize (16 L2-hit partial loads) -> no separate finalize kernel.
// w2d: per-thread redundant 600-edge winner scan (uniform s_loads) -> no scatter kernel, no atomics.
__global__ void prep_kernel(const float* __restrict__ states, const float* __restrict__ pacc,
                            const float* __restrict__ ehh_w, const float* __restrict__ anova,
                            const int* __restrict__ adj, const float* __restrict__ w1,
                            _Float16* __restrict__ A, _Float16* __restrict__ wt,
                            _Float16* __restrict__ w2dt) {
    __shared__ float tile[32][33];
    int vt = blockIdx.x;
    int tid = threadIdx.x;
    if (vt < 6400) {
        int t = vt * 256 + tid;   // t = b*800 + f
        int b = t / KDIM;
        int f = t - b * KDIM;
        int a = f >> 5, s = f & 31;
        float su = 0.f, sq = 0.f;
#pragma unroll
        for (int c = 0; c < 16; ++c) { su += pacc[c * 800 + f]; sq += pacc[12800 + c * 800 + f]; }
        float m = su * (1.f / BATCH);
        float var = sq * (1.f / BATCH) - m * m;
        float rs = rsqrtf(var + 1e-5f);
        float v = states[((size_t)a * BATCH + b) * 32 + s];
        A[t] = (_Float16)((v - m) * rs);
    } else if (vt < 8900) {
        int bb = vt - 6400;
        int n0 = (bb % 100) * 32, k0 = (bb / 100) * 32;
        int x = tid & 31, y = tid >> 5;
        for (int i = y; i < 32; i += 8)
            tile[i][x] = ehh_w[(size_t)(k0 + i) * EHH + n0 + x];
        __syncthreads();
        for (int i = y; i < 32; i += 8)
            wt[(size_t)(n0 + i) * KDIM + k0 + x] = (_Float16)tile[x][i];
    } else if (vt < 9213) {
        int t = (vt - 8900) * 256 + tid;   // t = a*3200 + h
        if (t < NAG * EHH) {
            int a = t / EHH, h = t - a * EHH;
            // sequential last-writer-wins: pass over adj[:,1] then adj[:,3]; later e wins
            int win = -1;
            for (int e = 0; e < NEDGE; ++e) if (adj[e * 4 + 1] == h) win = e;
            for (int e = 0; e < NEDGE; ++e) if (adj[e * 4 + 3] == h) win = NEDGE + e;
            float att = anova[(size_t)h * NAG + a];
            if (win >= 0)
                att += anova[(size_t)(EHH + adj[(win >= NEDGE ? win - NEDGE : win) * 4]) * NAG + a];
            const float* wp = w1 + ((size_t)a * EHH + h) * 12;
#pragma unroll
            for (int kk = 0; kk < 12; ++kk)
                w2dt[(size_t)(a * 12 + kk) * EHH + h] = (_Float16)(att * wp[kk]);
        }
    } else {
        int p = (vt - 9213) * 256 + tid;
        if (p < (NPAD - 300) * EHH / 8) {
            half8 z = {0, 0, 0, 0, 0, 0, 0, 0};
            ((half8*)(w2dt + (size_t)300 * EHH))[p] = z;
        }
    }
}

// ---------------- 128x128 MFMA GEMM, C = A(MxK) * B^T(NxK), fp16 k-contiguous, dbuf LDS ----------------
__device__ __forceinline__ void async16(const void* g, void* l) {
    __builtin_amdgcn_global_load_lds(
        (const __attribute__((address_space(1))) void*)(uintptr_t)g,
        (__attribute__((address_space(3))) void*)(unsigned)(uintptr_t)l, 16, 0, 0);
}

template <bool LEAKY_F16_OUT>
__global__ __launch_bounds__(256)
void gemm_bt(const _Float16* __restrict__ A, const _Float16* __restrict__ B,
             _Float16* __restrict__ Ch, float* __restrict__ Cf,
             int Ktot, int ldc, int kPerSplit, int slabStride) {
    __shared__ __attribute__((aligned(16))) _Float16 As[2][128 * 32];
    __shared__ __attribute__((aligned(16))) _Float16 Bs[2][128 * 32];
    const int tid = threadIdx.x;
    const int lane = tid & 63;
    const int wave = tid >> 6;            // 4 waves, 2x2
    const int wm = (wave >> 1) << 6;
    const int wn = (wave & 1) << 6;
    const int m0 = blockIdx.x << 7;
    const int n0 = blockIdx.y << 7;
    const int k0 = blockIdx.z * kPerSplit;
    const int nk = kPerSplit >> 5;

    const int srow = lane >> 2;
    const int scol = (lane & 3) << 3;
    const _Float16* gA0 = A + (size_t)(m0 + wave * 16 + srow) * Ktot + k0 + scol;
    const _Float16* gA1 = gA0 + (size_t)64 * Ktot;
    const _Float16* gB0 = B + (size_t)(n0 + wave * 16 + srow) * Ktot + k0 + scol;
    const _Float16* gB1 = gB0 + (size_t)64 * Ktot;
    const int lofs = wave * 512;

    f32x4 acc[4][4];
    const f32x4 zero = {0.f, 0.f, 0.f, 0.f};
#pragma unroll
    for (int i = 0; i < 4; ++i)
#pragma unroll
        for (int j = 0; j < 4; ++j) acc[i][j] = zero;

    const int fr = lane & 15;
    const int q8 = (lane >> 4) << 3;

    // prologue: stage tile 0 into buffer 0
    async16(gA0, As[0] + lofs);
    async16(gA1, As[0] + 2048 + lofs);
    async16(gB0, Bs[0] + lofs);
    async16(gB1, Bs[0] + 2048 + lofs);

    for (int kt = 0; kt < nk; ++kt) {
        const int cur = kt & 1;
        __syncthreads();   // drains vmcnt: buf[cur] staged; readers of buf[cur^1] done
        if (kt + 1 < nk) {
            const int ko = (kt + 1) << 5;
            const int nxt = cur ^ 1;
            async16(gA0 + ko, As[nxt] + lofs);
            async16(gA1 + ko, As[nxt] + 2048 + lofs);
            async16(gB0 + ko, Bs[nxt] + lofs);
            async16(gB1 + ko, Bs[nxt] + 2048 + lofs);
        }
        half8 av[4], bv[4];
#pragma unroll
        for (int i = 0; i < 4; ++i)
            av[i] = *(const half8*)(As[cur] + (wm + i * 16 + fr) * 32 + q8);
#pragma unroll
        for (int j = 0; j < 4; ++j)
            bv[j] = *(const half8*)(Bs[cur] + (wn + j * 16 + fr) * 32 + q8);
#pragma unroll
        for (int i = 0; i < 4; ++i)
#pragma unroll
            for (int j = 0; j < 4; ++j)
                acc[i][j] = __builtin_amdgcn_mfma_f32_16x16x32_f16(av[i], bv[j], acc[i][j], 0, 0, 0);
    }

    // C/D layout: col = lane&15, row = (lane>>4)*4 + reg  [m89-verified]
    const int r0 = (lane >> 4) << 2;
#pragma unroll
    for (int i = 0; i < 4; ++i)
#pragma unroll
        for (int j = 0; j < 4; ++j)
#pragma unroll
            for (int r = 0; r < 4; ++r) {
                int row = m0 + wm + i * 16 + r0 + r;
                int col = n0 + wn + j * 16 + fr;
                if (LEAKY_F16_OUT)
                    Ch[(size_t)row * ldc + col] = (_Float16)leaky(acc[i][j][r]);
                else
                    Cf[(size_t)blockIdx.z * slabStride + (size_t)row * ldc + col] = acc[i][j][r];
            }
}

// ---------------- tail: b-major mapping for coalesced Hp reads ----------------
__global__ void tail_kernel(const float* __restrict__ Hp, const float* __restrict__ b1,
                            const float* __restrict__ w2, const float* __restrict__ b2,
                            const float* __restrict__ w3, const float* __restrict__ b3,
                            const int* __restrict__ act, float* __restrict__ out) {
    int t = blockIdx.x * 256 + threadIdx.x;   // t = b*25 + a (b-major: lanes share Hp rows)
    int b = t / NAG;
    int a = t - b * NAG;
    const float* hp = Hp + (size_t)b * NPAD + a * 12;
    float h1[12];
#pragma unroll
    for (int k = 0; k < 12; ++k) {
        float s = b1[a * 12 + k];
#pragma unroll
        for (int ks = 0; ks < KSPLIT; ++ks) s += hp[(size_t)ks * BATCH * NPAD + k];
        h1[k] = leaky(s);
    }
    float h2[12];
#pragma unroll
    for (int j = 0; j < 12; ++j) {
        float s = b2[a * 12 + j];
#pragma unroll
        for (int k = 0; k < 12; ++k) s += h1[k] * w2[(a * 12 + k) * 12 + j];
        h2[j] = leaky(s);
    }
    int c = act[a * BATCH + b];
    float q = b3[a * 4 + c];
#pragma unroll
    for (int j = 0; j < 12; ++j) q += h2[j] * w3[(a * 12 + j) * 4 + c];
    out[a * BATCH + b] = q;
}

extern "C" void kernel_launch(void* const* d_in, const int* in_sizes, int n_in,
                              void* d_out, int out_size, void* d_ws, size_t ws_size,
                              hipStream_t stream) {
    (void)in_sizes; (void)n_in; (void)out_size; (void)ws_size;
    const float* states = (const float*)d_in[0];
    const float* ehh_w  = (const float*)d_in[1];
    const float* anova  = (const float*)d_in[2];
    const float* w1     = (const float*)d_in[3];
    const float* b1     = (const float*)d_in[4];
    const float* w2     = (const float*)d_in[5];
    const float* b2     = (const float*)d_in[6];
    const float* w3     = (const float*)d_in[7];
    const float* b3     = (const float*)d_in[8];
    const int* actions  = (const int*)d_in[9];
    const int* adj      = (const int*)d_in[10];
    float* out = (float*)d_out;

    char* ws = (char*)d_ws;
    float*     pacc = (float*)    (ws + 0);            // 2x16x800 f32 partials
    _Float16*  Abf  = (_Float16*) (ws + 102400);       // 2048x800
    _Float16*  WbT  = (_Float16*) (ws + 3379200);      // 3200x800
    _Float16*  W2dT = (_Float16*) (ws + 8499200);      // 384x3200
    _Float16*  emb  = (_Float16*) (ws + 10956800);     // 2048x3200
    float*     Hp   = (float*)    (ws + 24064000);     // KSPLIT x 2048x384 f32 (end ~39.8 MB)

    stats_part<<<dim3(25, 16), 256, 0, stream>>>(states, pacc);
    prep_kernel<<<9345, 256, 0, stream>>>(states, pacc, ehh_w, anova, adj, w1, Abf, WbT, W2dT);
    // GEMM1: emb = leaky(Abf @ WbT^T)   M=2048 N=3200 K=800
    gemm_bt<true><<<dim3(16, 25, 1), 256, 0, stream>>>(Abf, WbT, emb, nullptr, KDIM, EHH, KDIM, 0);
    // GEMM2: Hp = emb @ W2dT^T (split-K x5)   M=2048 N=384 K=3200
    gemm_bt<false><<<dim3(16, 3, KSPLIT), 256, 0, stream>>>(emb, W2dT, nullptr, Hp, EHH, NPAD,
                                                            EHH / KSPLIT, BATCH * NPAD);
    tail_kernel<<<(BATCH * NAG) / 256, 256, 0, stream>>>(Hp, b1, w2, b2, w3, b3, actions, out);
}

// Round 8
// 165.413 us; speedup vs baseline: 3.2427x; 1.0796x over previous
//
#include <hip/hip_runtime.h>
#include <cstdint>

#define NAG 25
#define EHH 3200      // EHH_HID
#define KDIM 800      // N_AGENT*N_S
#define BATCH 2048
#define NEDGE 300
#define NPAD 384      // 300 padded to 3x128
#define KSPLIT 5

typedef _Float16 half8 __attribute__((ext_vector_type(8)));
typedef float f32x4 __attribute__((ext_vector_type(4)));

__device__ __forceinline__ float leaky(float x) { return x >= 0.f ? x : 0.01f * x; }

// ---------------- batch-norm partial stats: (25 agents x 16 chunks), plain stores ----------------
__global__ void stats_part(const float* __restrict__ states, float* __restrict__ pacc) {
    int a = blockIdx.x;            // agent
    int chunk = blockIdx.y;        // 128 batch rows each
    int s = threadIdx.x & 31, ty = threadIdx.x >> 5;
    const float* base = states + ((size_t)a * BATCH + chunk * 128) * 32 + s;
    float sum = 0.f, sq = 0.f;
    for (int b = ty; b < 128; b += 8) {
        float v = base[(size_t)b * 32];
        sum += v; sq += v * v;
    }
    __shared__ float ls[8][32], lq[8][32];
    ls[ty][s] = sum; lq[ty][s] = sq;
    __syncthreads();
    if (ty == 0) {
#pragma unroll
        for (int i = 1; i < 8; ++i) { sum += ls[i][s]; sq += lq[i][s]; }
        pacc[chunk * 800 + a * 32 + s] = sum;
        pacc[12800 + chunk * 800 + a * 32 + s] = sq;
    }
}

// ---------------- finalize: mrs (mean/rsqrt) once; edge-winner scan once per h ----------------
// R7 lesson: folding these into prep cost 52M redundant VMEM loads (prep 60us). Do each ONCE.
__global__ void finalize_kernel(const float* __restrict__ pacc, const int* __restrict__ adj,
                                float* __restrict__ mrs, int* __restrict__ wsrc) {
    int bid = blockIdx.x, tid = threadIdx.x;
    if (bid < 4) {
        int f = bid * 256 + tid;
        if (f < 800) {
            float su = 0.f, sq = 0.f;
#pragma unroll
            for (int c = 0; c < 16; ++c) { su += pacc[c * 800 + f]; sq += pacc[12800 + c * 800 + f]; }
            float m = su * (1.f / BATCH);
            float var = sq * (1.f / BATCH) - m * m;
            mrs[f] = m;
            mrs[800 + f] = rsqrtf(var + 1e-5f);
        }
    } else {
        int h = (bid - 4) * 256 + tid;
        if (h < EHH) {
            // sequential last-writer-wins: pass over adj[:,1] then adj[:,3]; later e wins
            int win = -1;
            for (int e = 0; e < NEDGE; ++e) if (adj[e * 4 + 1] == h) win = e;
            for (int e = 0; e < NEDGE; ++e) if (adj[e * 4 + 3] == h) win = NEDGE + e;
            wsrc[h] = win >= 0 ? adj[(win >= NEDGE ? win - NEDGE : win) * 4] : -1;
        }
    }
}

// ---------------- fused prep: norma [0,6400) | wtrans [6400,8900) | w2d [8900,9213) | pad [9213,9345) ----
__global__ void prep_kernel(const float* __restrict__ states, const float* __restrict__ mrs,
                            const float* __restrict__ ehh_w, const float* __restrict__ anova,
                            const int* __restrict__ wsrc, const float* __restrict__ w1,
                            _Float16* __restrict__ A, _Float16* __restrict__ wt,
                            _Float16* __restrict__ w2dt) {
    __shared__ float tile[32][33];
    int vt = blockIdx.x;
    int tid = threadIdx.x;
    if (vt < 6400) {
        int t = vt * 256 + tid;   // t = b*800 + f
        int b = t / KDIM;
        int f = t - b * KDIM;
        int a = f >> 5, s = f & 31;
        float v = states[((size_t)a * BATCH + b) * 32 + s];
        A[t] = (_Float16)((v - mrs[f]) * mrs[800 + f]);
    } else if (vt < 8900) {
        int bb = vt - 6400;
        int n0 = (bb % 100) * 32, k0 = (bb / 100) * 32;
        int x = tid & 31, y = tid >> 5;
        for (int i = y; i < 32; i += 8)
            tile[i][x] = ehh_w[(size_t)(k0 + i) * EHH + n0 + x];
        __syncthreads();
        for (int i = y; i < 32; i += 8)
            wt[(size_t)(n0 + i) * KDIM + k0 + x] = (_Float16)tile[x][i];
    } else if (vt < 9213) {
        int t = (vt - 8900) * 256 + tid;   // t = a*3200 + h
        if (t < NAG * EHH) {
            int a = t / EHH, h = t - a * EHH;
            float att = anova[(size_t)h * NAG + a];
            int src = wsrc[h];
            if (src >= 0) att += anova[(size_t)(EHH + src) * NAG + a];
            const float* wp = w1 + ((size_t)a * EHH + h) * 12;
#pragma unroll
            for (int kk = 0; kk < 12; ++kk)
                w2dt[(size_t)(a * 12 + kk) * EHH + h] = (_Float16)(att * wp[kk]);
        }
    } else {
        int p = (vt - 9213) * 256 + tid;
        if (p < (NPAD - 300) * EHH / 8) {
            half8 z = {0, 0, 0, 0, 0, 0, 0, 0};
            ((half8*)(w2dt + (size_t)300 * EHH))[p] = z;
        }
    }
}

// ---------------- 128x128 MFMA GEMM, C = A(MxK) * B^T(NxK), fp16 k-contiguous, dbuf LDS ----------------
__device__ __forceinline__ void async16(const void* g, void* l) {
    __builtin_amdgcn_global_load_lds(
        (const __attribute__((address_space(1))) void*)(uintptr_t)g,
        (__attribute__((address_space(3))) void*)(unsigned)(uintptr_t)l, 16, 0, 0);
}

template <bool LEAKY_F16_OUT>
__global__ __launch_bounds__(256)
void gemm_bt(const _Float16* __restrict__ A, const _Float16* __restrict__ B,
             _Float16* __restrict__ Ch, float* __restrict__ Cf,
             int Ktot, int ldc, int kPerSplit, int slabStride) {
    __shared__ __attribute__((aligned(16))) _Float16 As[2][128 * 32];
    __shared__ __attribute__((aligned(16))) _Float16 Bs[2][128 * 32];
    const int tid = threadIdx.x;
    const int lane = tid & 63;
    const int wave = tid >> 6;            // 4 waves, 2x2
    const int wm = (wave >> 1) << 6;
    const int wn = (wave & 1) << 6;
    const int m0 = blockIdx.x << 7;
    const int n0 = blockIdx.y << 7;
    const int k0 = blockIdx.z * kPerSplit;
    const int nk = kPerSplit >> 5;

    const int srow = lane >> 2;
    const int scol = (lane & 3) << 3;
    const _Float16* gA0 = A + (size_t)(m0 + wave * 16 + srow) * Ktot + k0 + scol;
    const _Float16* gA1 = gA0 + (size_t)64 * Ktot;
    const _Float16* gB0 = B + (size_t)(n0 + wave * 16 + srow) * Ktot + k0 + scol;
    const _Float16* gB1 = gB0 + (size_t)64 * Ktot;
    const int lofs = wave * 512;

    f32x4 acc[4][4];
    const f32x4 zero = {0.f, 0.f, 0.f, 0.f};
#pragma unroll
    for (int i = 0; i < 4; ++i)
#pragma unroll
        for (int j = 0; j < 4; ++j) acc[i][j] = zero;

    const int fr = lane & 15;
    const int q8 = (lane >> 4) << 3;

    // prologue: stage tile 0 into buffer 0
    async16(gA0, As[0] + lofs);
    async16(gA1, As[0] + 2048 + lofs);
    async16(gB0, Bs[0] + lofs);
    async16(gB1, Bs[0] + 2048 + lofs);

    for (int kt = 0; kt < nk; ++kt) {
        const int cur = kt & 1;
        __syncthreads();   // drains vmcnt: buf[cur] staged; readers of buf[cur^1] done
        if (kt + 1 < nk) {
            const int ko = (kt + 1) << 5;
            const int nxt = cur ^ 1;
            async16(gA0 + ko, As[nxt] + lofs);
            async16(gA1 + ko, As[nxt] + 2048 + lofs);
            async16(gB0 + ko, Bs[nxt] + lofs);
            async16(gB1 + ko, Bs[nxt] + 2048 + lofs);
        }
        half8 av[4], bv[4];
#pragma unroll
        for (int i = 0; i < 4; ++i)
            av[i] = *(const half8*)(As[cur] + (wm + i * 16 + fr) * 32 + q8);
#pragma unroll
        for (int j = 0; j < 4; ++j)
            bv[j] = *(const half8*)(Bs[cur] + (wn + j * 16 + fr) * 32 + q8);
#pragma unroll
        for (int i = 0; i < 4; ++i)
#pragma unroll
            for (int j = 0; j < 4; ++j)
                acc[i][j] = __builtin_amdgcn_mfma_f32_16x16x32_f16(av[i], bv[j], acc[i][j], 0, 0, 0);
    }

    // C/D layout: col = lane&15, row = (lane>>4)*4 + reg  [m89-verified]
    const int r0 = (lane >> 4) << 2;
#pragma unroll
    for (int i = 0; i < 4; ++i)
#pragma unroll
        for (int j = 0; j < 4; ++j)
#pragma unroll
            for (int r = 0; r < 4; ++r) {
                int row = m0 + wm + i * 16 + r0 + r;
                int col = n0 + wn + j * 16 + fr;
                if (LEAKY_F16_OUT)
                    Ch[(size_t)row * ldc + col] = (_Float16)leaky(acc[i][j][r]);
                else
                    Cf[(size_t)blockIdx.z * slabStride + (size_t)row * ldc + col] = acc[i][j][r];
            }
}

// ---------------- tail: b-major mapping for coalesced Hp reads ----------------
__global__ void tail_kernel(const float* __restrict__ Hp, const float* __restrict__ b1,
                            const float* __restrict__ w2, const float* __restrict__ b2,
                            const float* __restrict__ w3, const float* __restrict__ b3,
                            const int* __restrict__ act, float* __restrict__ out) {
    int t = blockIdx.x * 256 + threadIdx.x;   // t = b*25 + a (b-major: lanes share Hp rows)
    int b = t / NAG;
    int a = t - b * NAG;
    const float* hp = Hp + (size_t)b * NPAD + a * 12;
    float h1[12];
#pragma unroll
    for (int k = 0; k < 12; ++k) {
        float s = b1[a * 12 + k];
#pragma unroll
        for (int ks = 0; ks < KSPLIT; ++ks) s += hp[(size_t)ks * BATCH * NPAD + k];
        h1[k] = leaky(s);
    }
    float h2[12];
#pragma unroll
    for (int j = 0; j < 12; ++j) {
        float s = b2[a * 12 + j];
#pragma unroll
        for (int k = 0; k < 12; ++k) s += h1[k] * w2[(a * 12 + k) * 12 + j];
        h2[j] = leaky(s);
    }
    int c = act[a * BATCH + b];
    float q = b3[a * 4 + c];
#pragma unroll
    for (int j = 0; j < 12; ++j) q += h2[j] * w3[(a * 12 + j) * 4 + c];
    out[a * BATCH + b] = q;
}

extern "C" void kernel_launch(void* const* d_in, const int* in_sizes, int n_in,
                              void* d_out, int out_size, void* d_ws, size_t ws_size,
                              hipStream_t stream) {
    (void)in_sizes; (void)n_in; (void)out_size; (void)ws_size;
    const float* states = (const float*)d_in[0];
    const float* ehh_w  = (const float*)d_in[1];
    const float* anova  = (const float*)d_in[2];
    const float* w1     = (const float*)d_in[3];
    const float* b1     = (const float*)d_in[4];
    const float* w2     = (const float*)d_in[5];
    const float* b2     = (const float*)d_in[6];
    const float* w3     = (const float*)d_in[7];
    const float* b3     = (const float*)d_in[8];
    const int* actions  = (const int*)d_in[9];
    const int* adj      = (const int*)d_in[10];
    float* out = (float*)d_out;

    char* ws = (char*)d_ws;
    float*     pacc = (float*)    (ws + 0);            // 2x16x800 f32 partials
    float*     mrs  = (float*)    (ws + 102400);       // 800 mean + 800 rsqrt
    int*       wsrc = (int*)      (ws + 109056);       // 3200 winner-src (-1 none)
    _Float16*  Abf  = (_Float16*) (ws + 122880);       // 2048x800
    _Float16*  WbT  = (_Float16*) (ws + 3399680);      // 3200x800
    _Float16*  W2dT = (_Float16*) (ws + 8519680);      // 384x3200
    _Float16*  emb  = (_Float16*) (ws + 10977280);     // 2048x3200
    float*     Hp   = (float*)    (ws + 24084480);     // KSPLIT x 2048x384 f32 (end ~39.8 MB)

    stats_part<<<dim3(25, 16), 256, 0, stream>>>(states, pacc);
    finalize_kernel<<<17, 256, 0, stream>>>(pacc, adj, mrs, wsrc);
    prep_kernel<<<9345, 256, 0, stream>>>(states, mrs, ehh_w, anova, wsrc, w1, Abf, WbT, W2dT);
    // GEMM1: emb = leaky(Abf @ WbT^T)   M=2048 N=3200 K=800
    gemm_bt<true><<<dim3(16, 25, 1), 256, 0, stream>>>(Abf, WbT, emb, nullptr, KDIM, EHH, KDIM, 0);
    // GEMM2: Hp = emb @ W2dT^T (split-K x5)   M=2048 N=384 K=3200
    gemm_bt<false><<<dim3(16, 3, KSPLIT), 256, 0, stream>>>(emb, W2dT, nullptr, Hp, EHH, NPAD,
                                                            EHH / KSPLIT, BATCH * NPAD);
    tail_kernel<<<(BATCH * NAG) / 256, 256, 0, stream>>>(Hp, b1, w2, b2, w3, b3, actions, out);
}